// Round 8
// baseline (215.471 us; speedup 1.0000x reference)
//
#include <hip/hip_runtime.h>
#include <hip/hip_bf16.h>
#include <hip/hip_fp16.h>

#define HC 64          // HEADS * C
#define D_IN 128
#define NEG_SLOPE 0.2f
#define BK 64          // nodes per scat bucket
#define BKQ 16         // nodes per aggs quarter-bucket
#define BCAP2 1536     // bucket capacity (mean 1024, 16 sigma margin)
#define NBIN 2048      // padded bucket count (actual 1563)
#define L2E 1.44269504f

using f32x4 = __attribute__((ext_vector_type(4))) float;
using f16x8 = __attribute__((ext_vector_type(8))) _Float16;
using f16x2 = __attribute__((ext_vector_type(2))) _Float16;

// ---------------- bfill[b] = b*BCAP2 ----------------
__global__ void k_iota(int* __restrict__ p, int n) {
    int i = blockIdx.x * blockDim.x + threadIdx.x;
    if (i < n) p[i] = i * BCAP2;
}

// ---------------- MFMA projection: R21 double-buffered pipeline ------------
// Old loop exposed the full HBM latency per trip (load x -> barrier ->
// compute -> barrier, 3 blocks/CU). New: x(trip+1) is loaded to REGISTERS
// during trip t's MFMA/stores, staged to the alternate LDS buffer at the top
// of the next iteration; ONE barrier per trip. (Write buf[t&1] and compute
// reads buf[t&1] sit between the same pair of barriers; readers of the buffer
// being overwritten finished one barrier earlier.)
__global__ __launch_bounds__(256, 3) void k_proj(
    const float* __restrict__ x,
    const float* __restrict__ Wl, const float* __restrict__ bl,
    const float* __restrict__ Wr, const float* __restrict__ br,
    __half* __restrict__ xlh, float* __restrict__ xr, int N) {
    __shared__ _Float16 sWT[128 * 136];     // 34 KB
    __shared__ _Float16 sX[2][32 * 136];    // 17 KB (double buffer)
    const int t = threadIdx.x;
    for (int idx = t; idx < 8192; idx += 256) {
        const int k = idx >> 6;
        const int c = idx & 63;
        sWT[c * 136 + k]        = (_Float16)Wl[idx];
        sWT[(c + 64) * 136 + k] = (_Float16)Wr[idx];
    }
    const int lane = t & 63;
    const int wave = t >> 6;
    const int m = lane & 15;
    const int q = lane >> 4;
    float bfu[2];
#pragma unroll
    for (int cc = 0; cc < 2; ++cc) {
        const int ct = wave * 2 + cc;
        const int ch = (ct & 3) * 16 + m;
        bfu[cc] = (ct < 4) ? bl[ch] : br[ch];
    }

    const int ntrip = N >> 5;              // 3125
    const int rr = t >> 5;                 // 0..7: my x-row group
    const int c4 = t & 31;                 // my float4 column
    int trip = blockIdx.x;
    int tb = 0;
    float4 xv[4];
    if (trip < ntrip) {
        const int i0 = trip << 5;
#pragma unroll
        for (int it = 0; it < 4; ++it)
            xv[it] = *(const float4*)(x + (size_t)(i0 + rr + 8 * it) * D_IN + c4 * 4);
    }
    for (; trip < ntrip; trip += gridDim.x, ++tb) {
        _Float16* sxb = &sX[tb & 1][0];
#pragma unroll
        for (int it = 0; it < 4; ++it) {
            _Float16* dp = &sxb[(rr + 8 * it) * 136 + c4 * 4];
            dp[0] = (_Float16)xv[it].x; dp[1] = (_Float16)xv[it].y;
            dp[2] = (_Float16)xv[it].z; dp[3] = (_Float16)xv[it].w;
        }
        __syncthreads();
        const int nxt = trip + gridDim.x;
        if (nxt < ntrip) {                 // prefetch next trip during compute
            const int i0n = nxt << 5;
#pragma unroll
            for (int it = 0; it < 4; ++it)
                xv[it] = *(const float4*)(x + (size_t)(i0n + rr + 8 * it) * D_IN + c4 * 4);
        }
        const int i0 = trip << 5;
        f16x8 af[2][4];
#pragma unroll
        for (int tt = 0; tt < 2; ++tt)
#pragma unroll
            for (int kk = 0; kk < 4; ++kk)
                af[tt][kk] = *(const f16x8*)&sxb[(tt * 16 + m) * 136 + kk * 32 + q * 8];
#pragma unroll
        for (int cc = 0; cc < 2; ++cc) {
            const int ct = wave * 2 + cc;
            const _Float16* bp = &sWT[(ct * 16 + m) * 136 + q * 8];
            f32x4 acc0 = {0.f, 0.f, 0.f, 0.f};
            f32x4 acc1 = {0.f, 0.f, 0.f, 0.f};
#pragma unroll
            for (int kk = 0; kk < 4; ++kk) {
                f16x8 bf = *(const f16x8*)(bp + kk * 32);
                acc0 = __builtin_amdgcn_mfma_f32_16x16x32_f16(af[0][kk], bf, acc0, 0, 0, 0);
                acc1 = __builtin_amdgcn_mfma_f32_16x16x32_f16(af[1][kk], bf, acc1, 0, 0, 0);
            }
            const float bv = bfu[cc];
            if (ct < 4) {
                const int ch = ct * 16 + m;
#pragma unroll
                for (int r = 0; r < 4; ++r) {
                    xlh[(size_t)(i0 + q * 4 + r) * HC + ch]      = __float2half(acc0[r] + bv);
                    xlh[(size_t)(i0 + 16 + q * 4 + r) * HC + ch] = __float2half(acc1[r] + bv);
                }
            } else {
                const int ch = (ct - 4) * 16 + m;
#pragma unroll
                for (int r = 0; r < 4; ++r) {
                    xr[(size_t)(i0 + q * 4 + r) * HC + ch]      = acc0[r] + bv;
                    xr[(size_t)(i0 + 16 + q * 4 + r) * HC + ch] = acc1[r] + bv;
                }
            }
        }
    }
}

// ============ CSR build: R21 = 2048 edges/block, 16KB LDS ===================
// R13 ran 391 blocks = 1.5 blocks/CU = 6 waves/CU (occupancy-starved).
// 2048 edges/block -> 782 blocks = 3.05/CU; h[] reused as scatter cursor
// (zeroed when consumed into bl[]) -> 16 KB. Fixed NBIN cost per block is
// ~24 wave-iterations (small vs halved per-block edge work).
__global__ __launch_bounds__(256) void k_scat1(const int* __restrict__ src,
                                               const int* __restrict__ dst, int E,
                                               int* __restrict__ bfill,
                                               unsigned* __restrict__ coarse) {
    __shared__ int h[NBIN], bl[NBIN];   // 16 KB
    const int t = threadIdx.x;
    for (int i = t; i < NBIN; i += 256) h[i] = 0;
    __syncthreads();
    const int beg = blockIdx.x * 2048;
    int4 d4[2], s4[2];
#pragma unroll
    for (int r = 0; r < 2; ++r) {
        const int idx = beg + 4 * t + r * 1024;
        if (idx < E) {
            d4[r] = *(const int4*)(dst + idx);
            s4[r] = *(const int4*)(src + idx);
        } else { d4[r] = make_int4(-1, -1, -1, -1); }
    }
#pragma unroll
    for (int r = 0; r < 2; ++r) {
        if (d4[r].x >= 0) {
            atomicAdd(&h[d4[r].x >> 6], 1);
            atomicAdd(&h[d4[r].y >> 6], 1);
            atomicAdd(&h[d4[r].z >> 6], 1);
            atomicAdd(&h[d4[r].w >> 6], 1);
        }
    }
    __syncthreads();
    for (int i = t; i < NBIN; i += 256) {
        const int hv = h[i];
        bl[i] = hv ? atomicAdd(&bfill[i], hv) : 0;
        h[i] = 0;                          // h becomes the scatter cursor
    }
    __syncthreads();
#pragma unroll
    for (int r = 0; r < 2; ++r) {
        if (d4[r].x >= 0) {
            const int dd[4] = {d4[r].x, d4[r].y, d4[r].z, d4[r].w};
            const int ss[4] = {s4[r].x, s4[r].y, s4[r].z, s4[r].w};
#pragma unroll
            for (int j = 0; j < 4; ++j) {
                const int bin = dd[j] >> 6;
                const int pos = atomicAdd(&h[bin], 1);
                coarse[bl[bin] + pos] = ((unsigned)ss[j] << 6) | (unsigned)(dd[j] & 63);
            }
        }
    }
}

// ------------- fused sort + aggregation + epilogue (R20, unchanged) ---------
// At its random-gather MLP bound: 105.8 MB HBM / 64.3 us = 1.69 TB/s ==
// 24 waves/CU x ~2 outstanding 128B gathers / ~900ns latency. Parked.
__device__ __forceinline__ float redpair(float v) {
    int a = __builtin_amdgcn_update_dpp(0, __float_as_int(v), 0xB1, 0xF, 0xF, true);
    return v + __int_as_float(a);   // quad_perm [1,0,3,2] = xor1
}
__device__ __forceinline__ float red8(float v) {
    int a = __builtin_amdgcn_update_dpp(0, __float_as_int(v), 0x128, 0xF, 0xF, true);
    return v + __int_as_float(a);   // row_ror:8 = lane^8 within 16-lane row
}

__global__ __launch_bounds__(256) void k_aggs(
    const __half* __restrict__ xlh, const float* __restrict__ xr,
    const float* __restrict__ att, const float* __restrict__ bias,
    const float* __restrict__ Wh, const float* __restrict__ bh,
    const int* __restrict__ bfill, const unsigned* __restrict__ coarse,
    float* __restrict__ out, int N) {
    __shared__ int s_src[BCAP2];          // 6 KB (worst-case skew safe)
    __shared__ int s_cnt[BKQ], s_off[BKQ], s_cur[BKQ], s_scan[BKQ];
    const int t = threadIdx.x;
    const int bkt  = blockIdx.x >> 2;
    const int quad = blockIdx.x & 3;
    const int eb = bkt * BCAP2;
    const int ee = bfill[bkt];            // eb + bucket edge count
    if (t < BKQ) { s_cnt[t] = 0; s_cur[t] = 0; }
    __syncthreads();
    // stage this quarter's entries in registers (<=6 per thread)
    unsigned er[6]; int nr = 0;
#pragma unroll
    for (int r = 0; r < 6; ++r) {
        const int idx = eb + t + r * 256;
        if (idx < ee) {
            const unsigned e = coarse[idx];
            if (((e >> 4) & 3u) == (unsigned)quad) er[nr++] = e;
        }
    }
    for (int k = 0; k < nr; ++k) atomicAdd(&s_cnt[er[k] & 15], 1);
    __syncthreads();
    if (t < BKQ) s_scan[t] = s_cnt[t];
    __syncthreads();
    for (int o = 1; o < BKQ; o <<= 1) {
        int v = (t < BKQ && t >= o) ? s_scan[t - o] : 0;
        __syncthreads();
        if (t < BKQ) s_scan[t] += v;
        __syncthreads();
    }
    if (t < BKQ) s_off[t] = s_scan[t] - s_cnt[t];
    __syncthreads();
    for (int k = 0; k < nr; ++k) {
        const int bin = er[k] & 15;
        const int pos = atomicAdd(&s_cur[bin], 1);
        s_src[s_off[bin] + pos] = (int)(er[k] >> 6);
    }
    __syncthreads();

    // ---- aggregation phase ----
    const int wave = t >> 6;
    const int lane = t & 63;
    const int sub  = lane & 7;      // channels 8sub..8sub+7
    const int slot = lane >> 3;     // edge slot 0..7
    const _Float16* xlhp = (const _Float16*)xlh;

    const float4 atA = *(const float4*)(att + 8 * sub);
    const float4 atB = *(const float4*)(att + 8 * sub + 4);
    f16x2 at[4];
    at[0][0] = (_Float16)(atA.x * L2E); at[0][1] = (_Float16)(atA.y * L2E);
    at[1][0] = (_Float16)(atA.z * L2E); at[1][1] = (_Float16)(atA.w * L2E);
    at[2][0] = (_Float16)(atB.x * L2E); at[2][1] = (_Float16)(atB.y * L2E);
    at[3][0] = (_Float16)(atB.z * L2E); at[3][1] = (_Float16)(atB.w * L2E);
    const f16x2 c02 = {(_Float16)NEG_SLOPE, (_Float16)NEG_SLOPE};
    const _Float16 h0 = (_Float16)0.f;
    const float4 biA = *(const float4*)(bias + 8 * sub);
    const float4 biB = *(const float4*)(bias + 8 * sub + 4);
    const float4 whA = *(const float4*)(Wh + 8 * sub);
    const float4 whB = *(const float4*)(Wh + 8 * sub + 4);
    const float bhv = bh[0];

    for (int k4 = 0; k4 < 4; ++k4) {
        const int nl = wave + 4 * k4;             // 0..15, interleaved
        const int i = bkt * 64 + quad * 16 + nl;
        if (i >= N) continue;
        const int beg = s_off[nl];
        const int cnt = s_cnt[nl];

        const float4 xrA = *(const float4*)(xr + ((size_t)i << 6) + 8 * sub);
        const float4 xrB = *(const float4*)(xr + ((size_t)i << 6) + 8 * sub + 4);
        f16x2 xri[4];
        xri[0][0] = (_Float16)xrA.x; xri[0][1] = (_Float16)xrA.y;
        xri[1][0] = (_Float16)xrA.z; xri[1][1] = (_Float16)xrA.w;
        xri[2][0] = (_Float16)xrB.x; xri[2][1] = (_Float16)xrB.y;
        xri[3][0] = (_Float16)xrB.z; xri[3][1] = (_Float16)xrB.w;
        const uint4 xliraw = *(const uint4*)(xlhp + ((size_t)i << 6) + 8 * sub);
        f16x2 xli[4];
        xli[0] = __builtin_bit_cast(f16x2, xliraw.x);
        xli[1] = __builtin_bit_cast(f16x2, xliraw.y);
        xli[2] = __builtin_bit_cast(f16x2, xliraw.z);
        xli[3] = __builtin_bit_cast(f16x2, xliraw.w);

        float t0 = 0.f;
#pragma unroll
        for (int c = 0; c < 4; ++c) {
            f16x2 w = xli[c] + xri[c];
            w = __builtin_elementwise_max(w, w * c02);
            t0 = __builtin_amdgcn_fdot2(at[c], w, t0, false);
        }
        t0 = redpair(t0);
        const _Float16 pe0h = (slot == 0) ? (_Float16)exp2f(t0) : h0;
        const f16x2 p0A = {pe0h, h0};
        const f16x2 p0B = {h0, pe0h};
        float s = (float)pe0h;
        float a[8];
#pragma unroll
        for (int c = 0; c < 4; ++c) {
            a[2 * c]     = __builtin_amdgcn_fdot2(xli[c], p0A, 0.f, false);
            a[2 * c + 1] = __builtin_amdgcn_fdot2(xli[c], p0B, 0.f, false);
        }

        int p = 0;
#define EDGE_GROUP(JEXPR, PRED)                                              \
    {                                                                        \
        const int jj = (JEXPR);                                              \
        const uint4 raw = *(const uint4*)(xlhp + ((size_t)jj << 6) + 8 * sub);\
        f16x2 xv[4];                                                         \
        xv[0] = __builtin_bit_cast(f16x2, raw.x);                            \
        xv[1] = __builtin_bit_cast(f16x2, raw.y);                            \
        xv[2] = __builtin_bit_cast(f16x2, raw.z);                            \
        xv[3] = __builtin_bit_cast(f16x2, raw.w);                            \
        float tt = 0.f;                                                      \
        _Pragma("unroll")                                                    \
        for (int c = 0; c < 4; ++c) {                                        \
            f16x2 w = xv[c] + xri[c];                                        \
            w = __builtin_elementwise_max(w, w * c02);                       \
            tt = __builtin_amdgcn_fdot2(at[c], w, tt, false);                \
        }                                                                    \
        tt = redpair(tt);                                                    \
        const _Float16 peh = (PRED) ? (_Float16)exp2f(tt) : h0;              \
        const f16x2 pA = {peh, h0};                                          \
        const f16x2 pB = {h0, peh};                                          \
        s += (float)peh;                                                     \
        _Pragma("unroll")                                                    \
        for (int c = 0; c < 4; ++c) {                                        \
            a[2 * c]     = __builtin_amdgcn_fdot2(xv[c], pA, a[2 * c], false);\
            a[2 * c + 1] = __builtin_amdgcn_fdot2(xv[c], pB, a[2 * c + 1], false);\
        }                                                                    \
    }
        for (; p + 16 <= cnt; p += 16) {
            const int j0 = s_src[beg + p + slot];
            const int j1 = s_src[beg + p + 8 + slot];
            EDGE_GROUP(j0, true)
            EDGE_GROUP(j1, true)
        }
        if (p + 8 <= cnt) {
            const int j0 = s_src[beg + p + slot];
            EDGE_GROUP(j0, true)
            p += 8;
        }
        const int rem = cnt - p;
        if (rem > 0) {
            const int idx = p + slot;
            const int j0 = s_src[beg + ((idx < cnt) ? idx : (cnt - 1))];
            EDGE_GROUP(j0, slot < rem)
        }
#undef EDGE_GROUP

        s = red8(s);  s += __shfl_xor(s, 16);  s += __shfl_xor(s, 32);
#pragma unroll
        for (int c = 0; c < 8; ++c) {
            a[c] = red8(a[c]);
            a[c] += __shfl_xor(a[c], 16);
            a[c] += __shfl_xor(a[c], 32);
        }
        const float inv = 1.f / s;
        float y = fmaxf(a[0] * inv + biA.x, 0.f) * whA.x
                + fmaxf(a[1] * inv + biA.y, 0.f) * whA.y
                + fmaxf(a[2] * inv + biA.z, 0.f) * whA.z
                + fmaxf(a[3] * inv + biA.w, 0.f) * whA.w
                + fmaxf(a[4] * inv + biB.x, 0.f) * whB.x
                + fmaxf(a[5] * inv + biB.y, 0.f) * whB.y
                + fmaxf(a[6] * inv + biB.z, 0.f) * whB.z
                + fmaxf(a[7] * inv + biB.w, 0.f) * whB.w;
        y += __shfl_xor(y, 1);
        y += __shfl_xor(y, 2);
        y += __shfl_xor(y, 4);
        if (lane == 0) out[i] = y + bhv;
    }
}

// ---------------- launch ----------------
extern "C" void kernel_launch(void* const* d_in, const int* in_sizes, int n_in,
                              void* d_out, int out_size, void* d_ws, size_t ws_size,
                              hipStream_t stream) {
    const float* x   = (const float*)d_in[0];
    const int*   ei  = (const int*)d_in[1];
    const float* Wl  = (const float*)d_in[2];
    const float* bl  = (const float*)d_in[3];
    const float* Wr  = (const float*)d_in[4];
    const float* br  = (const float*)d_in[5];
    const float* att = (const float*)d_in[6];
    const float* bias= (const float*)d_in[7];
    const float* Wh  = (const float*)d_in[8];
    const float* bh  = (const float*)d_in[9];
    float* out = (float*)d_out;

    const int N = in_sizes[0] / D_IN;      // 100000
    const int E = in_sizes[1] / 2;         // 1600000
    const int* src = ei;
    const int* dst = ei + E;
    const int nbkt = (N + BK - 1) / BK;    // 1563

    // workspace layout (256B aligned)
    auto align = [](size_t v) { return (v + 255) & ~(size_t)255; };
    char* ws = (char*)d_ws;
    size_t off = 0;
    __half* xlh     = (__half*)(ws + off);   off = align(off + (size_t)N * HC * 2);
    float* xr       = (float*)(ws + off);    off = align(off + (size_t)N * HC * 4);
    int*   bfill    = (int*)(ws + off);      off = align(off + NBIN * 4);
    unsigned* coarse= (unsigned*)(ws + off); off = align(off + (size_t)NBIN * BCAP2 * 4);
    (void)ws_size;

    k_iota<<<8, 256, 0, stream>>>(bfill, NBIN);

    k_proj<<<1024, 256, 0, stream>>>(x, Wl, bl, Wr, br, xlh, xr, N);

    k_scat1<<<(E + 2047) / 2048, 256, 0, stream>>>(src, dst, E, bfill, coarse);

    k_aggs<<<nbkt * 4, 256, 0, stream>>>(xlh, xr, att, bias, Wh, bh,
                                         bfill, coarse, out, N);
}

// Round 9
// 212.754 us; speedup vs baseline: 1.0128x; 1.0128x over previous
//
#include <hip/hip_runtime.h>
#include <hip/hip_bf16.h>
#include <hip/hip_fp16.h>

#define HC 64          // HEADS * C
#define D_IN 128
#define NEG_SLOPE 0.2f
#define BK 64          // nodes per scat bucket
#define BKQ 16         // nodes per aggs quarter-bucket
#define BCAP2 1536     // bucket capacity (mean 1024, 16 sigma margin)
#define NBIN 2048      // padded bucket count (actual 1563)
#define L2E 1.44269504f

using f32x4 = __attribute__((ext_vector_type(4))) float;
using f16x8 = __attribute__((ext_vector_type(8))) _Float16;
using f16x2 = __attribute__((ext_vector_type(2))) _Float16;

// ---------------- bfill[b] = b*BCAP2 ----------------
__global__ void k_iota(int* __restrict__ p, int n) {
    int i = blockIdx.x * blockDim.x + threadIdx.x;
    if (i < n) p[i] = i * BCAP2;
}

// ---------------- MFMA projection: R22 coalesced-store epilogue ------------
// Theory: all prior proj variants shared the scalar store pattern (16 lanes
// cover a 32B fragment of a 128B xlh row; 800K partial-line write requests
// total) and all measured the same — the stores are the invariant suspect.
// R22: W fragments in registers (R17 pattern, measured neutral), outputs
// staged to 12KB LDS, then copied out as fully-linear uint4 stores
// (4KB xlh + 8KB xr contiguous per 32-node trip). 2 barriers/trip.
__global__ __launch_bounds__(256, 4) void k_proj(
    const float* __restrict__ x,
    const float* __restrict__ Wl, const float* __restrict__ bl,
    const float* __restrict__ Wr, const float* __restrict__ br,
    __half* __restrict__ xlh, float* __restrict__ xr, int N) {
    __shared__ _Float16 sH[32 * 64];    // 4 KB xlh staging
    __shared__ float    sF[32 * 64];    // 8 KB xr staging
    const int t = threadIdx.x;
    const int lane = t & 63;
    const int wave = t >> 6;
    const int m = lane & 15;
    const int q = lane >> 4;

    // hoist B (weight) fragments: bf[cc][kk][e] = W[kk*32+q*8+e][ch]
    f16x8 bf[2][4];
    float bfu[2];
#pragma unroll
    for (int cc = 0; cc < 2; ++cc) {
        const int ct = wave * 2 + cc;
        const int ch = (ct & 3) * 16 + m;
        const float* W = (ct < 4) ? Wl : Wr;
        bfu[cc] = (ct < 4) ? bl[ch] : br[ch];
#pragma unroll
        for (int kk = 0; kk < 4; ++kk) {
            const float* wp = W + (size_t)(kk * 32 + q * 8) * 64 + ch;
            f16x8 v;
#pragma unroll
            for (int e = 0; e < 8; ++e)
                v[e] = (_Float16)wp[(size_t)e * 64];
            bf[cc][kk] = v;
        }
    }

    const int ntrip = N >> 5;              // 3125 (N % 32 == 0)
    for (int trip = blockIdx.x; trip < ntrip; trip += gridDim.x) {
        const int i0 = trip << 5;
        // A fragments straight from global (R17 pattern)
        f16x8 af[2][4];
#pragma unroll
        for (int tt = 0; tt < 2; ++tt) {
            const float* xp = x + (size_t)(i0 + tt * 16 + m) * D_IN + q * 8;
#pragma unroll
            for (int kk = 0; kk < 4; ++kk) {
                const float4 f0 = *(const float4*)(xp + kk * 32);
                const float4 f1 = *(const float4*)(xp + kk * 32 + 4);
                f16x8 v;
                v[0] = (_Float16)f0.x; v[1] = (_Float16)f0.y;
                v[2] = (_Float16)f0.z; v[3] = (_Float16)f0.w;
                v[4] = (_Float16)f1.x; v[5] = (_Float16)f1.y;
                v[6] = (_Float16)f1.z; v[7] = (_Float16)f1.w;
                af[tt][kk] = v;
            }
        }
#pragma unroll
        for (int cc = 0; cc < 2; ++cc) {
            const int ct = wave * 2 + cc;
            f32x4 acc0 = {0.f, 0.f, 0.f, 0.f};
            f32x4 acc1 = {0.f, 0.f, 0.f, 0.f};
#pragma unroll
            for (int kk = 0; kk < 4; ++kk) {
                acc0 = __builtin_amdgcn_mfma_f32_16x16x32_f16(af[0][kk], bf[cc][kk], acc0, 0, 0, 0);
                acc1 = __builtin_amdgcn_mfma_f32_16x16x32_f16(af[1][kk], bf[cc][kk], acc1, 0, 0, 0);
            }
            const float bv = bfu[cc];
            if (ct < 4) {                  // xlh staging (waves 0-1)
                const int ch = ct * 16 + m;
#pragma unroll
                for (int r = 0; r < 4; ++r) {
                    sH[(q * 4 + r) * 64 + ch]      = (_Float16)(acc0[r] + bv);
                    sH[(16 + q * 4 + r) * 64 + ch] = (_Float16)(acc1[r] + bv);
                }
            } else {                       // xr staging (waves 2-3)
                const int ch = (ct - 4) * 16 + m;
#pragma unroll
                for (int r = 0; r < 4; ++r) {
                    sF[(q * 4 + r) * 64 + ch]      = acc0[r] + bv;
                    sF[(16 + q * 4 + r) * 64 + ch] = acc1[r] + bv;
                }
            }
        }
        __syncthreads();                   // staging complete
        // fully-coalesced wide copy-out: 4KB + 8KB contiguous
        {
            const uint4* srcH = (const uint4*)sH;
            uint4* dstH = (uint4*)(xlh + (size_t)i0 * 64);
            dstH[t] = srcH[t];             // 256 x 16B = 4 KB
            const uint4* srcF = (const uint4*)sF;
            uint4* dstF = (uint4*)(xr + (size_t)i0 * 64);
            dstF[t]       = srcF[t];       // 2 x 256 x 16B = 8 KB
            dstF[t + 256] = srcF[t + 256];
        }
        __syncthreads();                   // staging reads done before reuse
    }
}

// ============ CSR build (R13 verbatim, ~23 us known-good) ===================
__global__ __launch_bounds__(256) void k_scat1(const int* __restrict__ src,
                                               const int* __restrict__ dst, int E,
                                               int* __restrict__ bfill,
                                               unsigned* __restrict__ coarse) {
    __shared__ int h[NBIN], bl[NBIN], cur[NBIN];   // 24 KB
    const int t = threadIdx.x;
    for (int i = t; i < NBIN; i += 256) { h[i] = 0; cur[i] = 0; }
    __syncthreads();
    const int beg = blockIdx.x * 4096;
    int4 d4[4], s4[4];
#pragma unroll
    for (int r = 0; r < 4; ++r) {
        const int idx = beg + 4 * t + r * 1024;
        if (idx < E) {
            d4[r] = *(const int4*)(dst + idx);
            s4[r] = *(const int4*)(src + idx);
        } else { d4[r] = make_int4(-1, -1, -1, -1); }
    }
#pragma unroll
    for (int r = 0; r < 4; ++r) {
        if (d4[r].x >= 0) {
            atomicAdd(&h[d4[r].x >> 6], 1);
            atomicAdd(&h[d4[r].y >> 6], 1);
            atomicAdd(&h[d4[r].z >> 6], 1);
            atomicAdd(&h[d4[r].w >> 6], 1);
        }
    }
    __syncthreads();
    for (int i = t; i < NBIN; i += 256)
        bl[i] = h[i] ? atomicAdd(&bfill[i], h[i]) : 0;
    __syncthreads();
#pragma unroll
    for (int r = 0; r < 4; ++r) {
        if (d4[r].x >= 0) {
            const int dd[4] = {d4[r].x, d4[r].y, d4[r].z, d4[r].w};
            const int ss[4] = {s4[r].x, s4[r].y, s4[r].z, s4[r].w};
#pragma unroll
            for (int j = 0; j < 4; ++j) {
                const int bin = dd[j] >> 6;
                const int pos = atomicAdd(&cur[bin], 1);
                coarse[bl[bin] + pos] = ((unsigned)ss[j] << 6) | (unsigned)(dd[j] & 63);
            }
        }
    }
}

// ------------- fused sort + aggregation + epilogue (R20, unchanged) ---------
// At its random-gather MLP bound: 105.8 MB HBM / 64.3 us = 1.69 TB/s ==
// 24 waves/CU x ~2 outstanding 128B gathers / ~900ns latency. Parked.
__device__ __forceinline__ float redpair(float v) {
    int a = __builtin_amdgcn_update_dpp(0, __float_as_int(v), 0xB1, 0xF, 0xF, true);
    return v + __int_as_float(a);   // quad_perm [1,0,3,2] = xor1
}
__device__ __forceinline__ float red8(float v) {
    int a = __builtin_amdgcn_update_dpp(0, __float_as_int(v), 0x128, 0xF, 0xF, true);
    return v + __int_as_float(a);   // row_ror:8 = lane^8 within 16-lane row
}

__global__ __launch_bounds__(256) void k_aggs(
    const __half* __restrict__ xlh, const float* __restrict__ xr,
    const float* __restrict__ att, const float* __restrict__ bias,
    const float* __restrict__ Wh, const float* __restrict__ bh,
    const int* __restrict__ bfill, const unsigned* __restrict__ coarse,
    float* __restrict__ out, int N) {
    __shared__ int s_src[BCAP2];          // 6 KB (worst-case skew safe)
    __shared__ int s_cnt[BKQ], s_off[BKQ], s_cur[BKQ], s_scan[BKQ];
    const int t = threadIdx.x;
    const int bkt  = blockIdx.x >> 2;
    const int quad = blockIdx.x & 3;
    const int eb = bkt * BCAP2;
    const int ee = bfill[bkt];            // eb + bucket edge count
    if (t < BKQ) { s_cnt[t] = 0; s_cur[t] = 0; }
    __syncthreads();
    // stage this quarter's entries in registers (<=6 per thread)
    unsigned er[6]; int nr = 0;
#pragma unroll
    for (int r = 0; r < 6; ++r) {
        const int idx = eb + t + r * 256;
        if (idx < ee) {
            const unsigned e = coarse[idx];
            if (((e >> 4) & 3u) == (unsigned)quad) er[nr++] = e;
        }
    }
    for (int k = 0; k < nr; ++k) atomicAdd(&s_cnt[er[k] & 15], 1);
    __syncthreads();
    if (t < BKQ) s_scan[t] = s_cnt[t];
    __syncthreads();
    for (int o = 1; o < BKQ; o <<= 1) {
        int v = (t < BKQ && t >= o) ? s_scan[t - o] : 0;
        __syncthreads();
        if (t < BKQ) s_scan[t] += v;
        __syncthreads();
    }
    if (t < BKQ) s_off[t] = s_scan[t] - s_cnt[t];
    __syncthreads();
    for (int k = 0; k < nr; ++k) {
        const int bin = er[k] & 15;
        const int pos = atomicAdd(&s_cur[bin], 1);
        s_src[s_off[bin] + pos] = (int)(er[k] >> 6);
    }
    __syncthreads();

    // ---- aggregation phase ----
    const int wave = t >> 6;
    const int lane = t & 63;
    const int sub  = lane & 7;      // channels 8sub..8sub+7
    const int slot = lane >> 3;     // edge slot 0..7
    const _Float16* xlhp = (const _Float16*)xlh;

    const float4 atA = *(const float4*)(att + 8 * sub);
    const float4 atB = *(const float4*)(att + 8 * sub + 4);
    f16x2 at[4];
    at[0][0] = (_Float16)(atA.x * L2E); at[0][1] = (_Float16)(atA.y * L2E);
    at[1][0] = (_Float16)(atA.z * L2E); at[1][1] = (_Float16)(atA.w * L2E);
    at[2][0] = (_Float16)(atB.x * L2E); at[2][1] = (_Float16)(atB.y * L2E);
    at[3][0] = (_Float16)(atB.z * L2E); at[3][1] = (_Float16)(atB.w * L2E);
    const f16x2 c02 = {(_Float16)NEG_SLOPE, (_Float16)NEG_SLOPE};
    const _Float16 h0 = (_Float16)0.f;
    const float4 biA = *(const float4*)(bias + 8 * sub);
    const float4 biB = *(const float4*)(bias + 8 * sub + 4);
    const float4 whA = *(const float4*)(Wh + 8 * sub);
    const float4 whB = *(const float4*)(Wh + 8 * sub + 4);
    const float bhv = bh[0];

    for (int k4 = 0; k4 < 4; ++k4) {
        const int nl = wave + 4 * k4;             // 0..15, interleaved
        const int i = bkt * 64 + quad * 16 + nl;
        if (i >= N) continue;
        const int beg = s_off[nl];
        const int cnt = s_cnt[nl];

        const float4 xrA = *(const float4*)(xr + ((size_t)i << 6) + 8 * sub);
        const float4 xrB = *(const float4*)(xr + ((size_t)i << 6) + 8 * sub + 4);
        f16x2 xri[4];
        xri[0][0] = (_Float16)xrA.x; xri[0][1] = (_Float16)xrA.y;
        xri[1][0] = (_Float16)xrA.z; xri[1][1] = (_Float16)xrA.w;
        xri[2][0] = (_Float16)xrB.x; xri[2][1] = (_Float16)xrB.y;
        xri[3][0] = (_Float16)xrB.z; xri[3][1] = (_Float16)xrB.w;
        const uint4 xliraw = *(const uint4*)(xlhp + ((size_t)i << 6) + 8 * sub);
        f16x2 xli[4];
        xli[0] = __builtin_bit_cast(f16x2, xliraw.x);
        xli[1] = __builtin_bit_cast(f16x2, xliraw.y);
        xli[2] = __builtin_bit_cast(f16x2, xliraw.z);
        xli[3] = __builtin_bit_cast(f16x2, xliraw.w);

        float t0 = 0.f;
#pragma unroll
        for (int c = 0; c < 4; ++c) {
            f16x2 w = xli[c] + xri[c];
            w = __builtin_elementwise_max(w, w * c02);
            t0 = __builtin_amdgcn_fdot2(at[c], w, t0, false);
        }
        t0 = redpair(t0);
        const _Float16 pe0h = (slot == 0) ? (_Float16)exp2f(t0) : h0;
        const f16x2 p0A = {pe0h, h0};
        const f16x2 p0B = {h0, pe0h};
        float s = (float)pe0h;
        float a[8];
#pragma unroll
        for (int c = 0; c < 4; ++c) {
            a[2 * c]     = __builtin_amdgcn_fdot2(xli[c], p0A, 0.f, false);
            a[2 * c + 1] = __builtin_amdgcn_fdot2(xli[c], p0B, 0.f, false);
        }

        int p = 0;
#define EDGE_GROUP(JEXPR, PRED)                                              \
    {                                                                        \
        const int jj = (JEXPR);                                              \
        const uint4 raw = *(const uint4*)(xlhp + ((size_t)jj << 6) + 8 * sub);\
        f16x2 xv[4];                                                         \
        xv[0] = __builtin_bit_cast(f16x2, raw.x);                            \
        xv[1] = __builtin_bit_cast(f16x2, raw.y);                            \
        xv[2] = __builtin_bit_cast(f16x2, raw.z);                            \
        xv[3] = __builtin_bit_cast(f16x2, raw.w);                            \
        float tt = 0.f;                                                      \
        _Pragma("unroll")                                                    \
        for (int c = 0; c < 4; ++c) {                                        \
            f16x2 w = xv[c] + xri[c];                                        \
            w = __builtin_elementwise_max(w, w * c02);                       \
            tt = __builtin_amdgcn_fdot2(at[c], w, tt, false);                \
        }                                                                    \
        tt = redpair(tt);                                                    \
        const _Float16 peh = (PRED) ? (_Float16)exp2f(tt) : h0;              \
        const f16x2 pA = {peh, h0};                                          \
        const f16x2 pB = {h0, peh};                                          \
        s += (float)peh;                                                     \
        _Pragma("unroll")                                                    \
        for (int c = 0; c < 4; ++c) {                                        \
            a[2 * c]     = __builtin_amdgcn_fdot2(xv[c], pA, a[2 * c], false);\
            a[2 * c + 1] = __builtin_amdgcn_fdot2(xv[c], pB, a[2 * c + 1], false);\
        }                                                                    \
    }
        for (; p + 16 <= cnt; p += 16) {
            const int j0 = s_src[beg + p + slot];
            const int j1 = s_src[beg + p + 8 + slot];
            EDGE_GROUP(j0, true)
            EDGE_GROUP(j1, true)
        }
        if (p + 8 <= cnt) {
            const int j0 = s_src[beg + p + slot];
            EDGE_GROUP(j0, true)
            p += 8;
        }
        const int rem = cnt - p;
        if (rem > 0) {
            const int idx = p + slot;
            const int j0 = s_src[beg + ((idx < cnt) ? idx : (cnt - 1))];
            EDGE_GROUP(j0, slot < rem)
        }
#undef EDGE_GROUP

        s = red8(s);  s += __shfl_xor(s, 16);  s += __shfl_xor(s, 32);
#pragma unroll
        for (int c = 0; c < 8; ++c) {
            a[c] = red8(a[c]);
            a[c] += __shfl_xor(a[c], 16);
            a[c] += __shfl_xor(a[c], 32);
        }
        const float inv = 1.f / s;
        float y = fmaxf(a[0] * inv + biA.x, 0.f) * whA.x
                + fmaxf(a[1] * inv + biA.y, 0.f) * whA.y
                + fmaxf(a[2] * inv + biA.z, 0.f) * whA.z
                + fmaxf(a[3] * inv + biA.w, 0.f) * whA.w
                + fmaxf(a[4] * inv + biB.x, 0.f) * whB.x
                + fmaxf(a[5] * inv + biB.y, 0.f) * whB.y
                + fmaxf(a[6] * inv + biB.z, 0.f) * whB.z
                + fmaxf(a[7] * inv + biB.w, 0.f) * whB.w;
        y += __shfl_xor(y, 1);
        y += __shfl_xor(y, 2);
        y += __shfl_xor(y, 4);
        if (lane == 0) out[i] = y + bhv;
    }
}

// ---------------- launch ----------------
extern "C" void kernel_launch(void* const* d_in, const int* in_sizes, int n_in,
                              void* d_out, int out_size, void* d_ws, size_t ws_size,
                              hipStream_t stream) {
    const float* x   = (const float*)d_in[0];
    const int*   ei  = (const int*)d_in[1];
    const float* Wl  = (const float*)d_in[2];
    const float* bl  = (const float*)d_in[3];
    const float* Wr  = (const float*)d_in[4];
    const float* br  = (const float*)d_in[5];
    const float* att = (const float*)d_in[6];
    const float* bias= (const float*)d_in[7];
    const float* Wh  = (const float*)d_in[8];
    const float* bh  = (const float*)d_in[9];
    float* out = (float*)d_out;

    const int N = in_sizes[0] / D_IN;      // 100000
    const int E = in_sizes[1] / 2;         // 1600000
    const int* src = ei;
    const int* dst = ei + E;
    const int nbkt = (N + BK - 1) / BK;    // 1563

    // workspace layout (256B aligned)
    auto align = [](size_t v) { return (v + 255) & ~(size_t)255; };
    char* ws = (char*)d_ws;
    size_t off = 0;
    __half* xlh     = (__half*)(ws + off);   off = align(off + (size_t)N * HC * 2);
    float* xr       = (float*)(ws + off);    off = align(off + (size_t)N * HC * 4);
    int*   bfill    = (int*)(ws + off);      off = align(off + NBIN * 4);
    unsigned* coarse= (unsigned*)(ws + off); off = align(off + (size_t)NBIN * BCAP2 * 4);
    (void)ws_size;

    k_iota<<<8, 256, 0, stream>>>(bfill, NBIN);

    k_proj<<<1024, 256, 0, stream>>>(x, Wl, bl, Wr, br, xlh, xr, N);

    k_scat1<<<(E + 4095) / 4096, 256, 0, stream>>>(src, dst, E, bfill, coarse);

    k_aggs<<<nbkt * 4, 256, 0, stream>>>(xlh, xr, att, bias, Wh, bh,
                                         bfill, coarse, out, N);
}

// Round 10
// 201.724 us; speedup vs baseline: 1.0681x; 1.0547x over previous
//
#include <hip/hip_runtime.h>
#include <hip/hip_bf16.h>
#include <hip/hip_fp16.h>

#define HC 64          // HEADS * C
#define D_IN 128
#define NEG_SLOPE 0.2f
#define BK 64          // nodes per scat bucket
#define BKQ 16         // nodes per aggs quarter-bucket
#define BCAP2 1536     // bucket capacity (mean 1024, 16 sigma margin)
#define NBIN 2048      // padded bucket count (actual 1563)
#define L2E 1.44269504f

using f32x4 = __attribute__((ext_vector_type(4))) float;
using f16x8 = __attribute__((ext_vector_type(8))) _Float16;
using f16x2 = __attribute__((ext_vector_type(2))) _Float16;

// ---------------- bfill[b] = b*BCAP2 ----------------
__global__ void k_iota(int* __restrict__ p, int n) {
    int i = blockIdx.x * blockDim.x + threadIdx.x;
    if (i < n) p[i] = i * BCAP2;
}

// ============ fused proj + scat (best-measured roles, clean pairing) ========
// R23: R5's fusion retried without confounds. Blocks [0,391): R13 LDS-
// histogram scatter (latency-bound, now 3 blocks/CU vs 1.5 standalone).
// Blocks [391, 391+1024): R0-LDS MFMA projection (2-barrier, best-measured).
// Roles share a 42.5KB LDS union; both fit 3 blocks/CU (launch_bounds 3).
// scat's ~23.5us of latency-bound work hides under proj's streaming work.
// xr is now stored as f16 (same f32->f16 rounding aggs already applied ->
// bit-identical results; -12.8MB proj writes, -12.8MB aggs reads).
__global__ __launch_bounds__(256, 3) void k_projscat(
    const float* __restrict__ x,
    const float* __restrict__ Wl, const float* __restrict__ bl,
    const float* __restrict__ Wr, const float* __restrict__ br,
    __half* __restrict__ xlh, __half* __restrict__ xrh,
    const int* __restrict__ src, const int* __restrict__ dst, int E,
    int* __restrict__ bfill, unsigned* __restrict__ coarse, int N) {
    __shared__ __align__(16) char smem[43520];   // max(proj 42.5KB, scat 24KB)
    const int t = threadIdx.x;
    const int nscat = (E + 4095) >> 12;          // 391

    if ((int)blockIdx.x < nscat) {
        // ---------------- scat role (R13 verbatim) ----------------
        int* h   = (int*)smem;                   // 8 KB
        int* sbl = (int*)(smem + 8192);          // 8 KB
        int* cur = (int*)(smem + 16384);         // 8 KB
        for (int i = t; i < NBIN; i += 256) { h[i] = 0; cur[i] = 0; }
        __syncthreads();
        const int beg = blockIdx.x * 4096;
        int4 d4[4], s4[4];
#pragma unroll
        for (int r = 0; r < 4; ++r) {
            const int idx = beg + 4 * t + r * 1024;
            if (idx < E) {
                d4[r] = *(const int4*)(dst + idx);
                s4[r] = *(const int4*)(src + idx);
            } else { d4[r] = make_int4(-1, -1, -1, -1); }
        }
#pragma unroll
        for (int r = 0; r < 4; ++r) {
            if (d4[r].x >= 0) {
                atomicAdd(&h[d4[r].x >> 6], 1);
                atomicAdd(&h[d4[r].y >> 6], 1);
                atomicAdd(&h[d4[r].z >> 6], 1);
                atomicAdd(&h[d4[r].w >> 6], 1);
            }
        }
        __syncthreads();
        for (int i = t; i < NBIN; i += 256)
            sbl[i] = h[i] ? atomicAdd(&bfill[i], h[i]) : 0;
        __syncthreads();
#pragma unroll
        for (int r = 0; r < 4; ++r) {
            if (d4[r].x >= 0) {
                const int dd[4] = {d4[r].x, d4[r].y, d4[r].z, d4[r].w};
                const int ss[4] = {s4[r].x, s4[r].y, s4[r].z, s4[r].w};
#pragma unroll
                for (int j = 0; j < 4; ++j) {
                    const int bin = dd[j] >> 6;
                    const int pos = atomicAdd(&cur[bin], 1);
                    coarse[sbl[bin] + pos] = ((unsigned)ss[j] << 6) | (unsigned)(dd[j] & 63);
                }
            }
        }
        return;
    }

    // ---------------- proj role (R0-LDS, best measured) ----------------
    _Float16* sWT = (_Float16*)smem;             // 34 KB: sWT[c*136+k]
    _Float16* sX  = (_Float16*)(smem + 34816);   // 8.5 KB: sX[r*136+k]
    const int pb  = blockIdx.x - nscat;
    const int npb = gridDim.x - nscat;           // 1024
    for (int idx = t; idx < 8192; idx += 256) {
        const int k = idx >> 6;
        const int c = idx & 63;
        sWT[c * 136 + k]        = (_Float16)Wl[idx];
        sWT[(c + 64) * 136 + k] = (_Float16)Wr[idx];
    }
    const int lane = t & 63;
    const int wave = t >> 6;
    const int m = lane & 15;
    const int q = lane >> 4;
    float bfu[2];
#pragma unroll
    for (int cc = 0; cc < 2; ++cc) {
        const int ct = wave * 2 + cc;
        const int ch = (ct & 3) * 16 + m;
        bfu[cc] = (ct < 4) ? bl[ch] : br[ch];
    }
    __syncthreads();

    const int ntrip = N >> 5;
    for (int trip = pb; trip < ntrip; trip += npb) {
        const int i0 = trip << 5;
        for (int c = t; c < 1024; c += 256) {
            const int r = c >> 5, c4 = c & 31;
            float4 v = ((const float4*)(x + (size_t)(i0 + r) * D_IN))[c4];
            _Float16* dp = &sX[r * 136 + c4 * 4];
            dp[0] = (_Float16)v.x; dp[1] = (_Float16)v.y;
            dp[2] = (_Float16)v.z; dp[3] = (_Float16)v.w;
        }
        __syncthreads();
        f16x8 af[2][4];
#pragma unroll
        for (int tt = 0; tt < 2; ++tt)
#pragma unroll
            for (int kk = 0; kk < 4; ++kk)
                af[tt][kk] = *(const f16x8*)&sX[(tt * 16 + m) * 136 + kk * 32 + q * 8];
#pragma unroll
        for (int cc = 0; cc < 2; ++cc) {
            const int ct = wave * 2 + cc;
            const _Float16* bp = &sWT[(ct * 16 + m) * 136 + q * 8];
            f32x4 acc0 = {0.f, 0.f, 0.f, 0.f};
            f32x4 acc1 = {0.f, 0.f, 0.f, 0.f};
#pragma unroll
            for (int kk = 0; kk < 4; ++kk) {
                f16x8 bf = *(const f16x8*)(bp + kk * 32);
                acc0 = __builtin_amdgcn_mfma_f32_16x16x32_f16(af[0][kk], bf, acc0, 0, 0, 0);
                acc1 = __builtin_amdgcn_mfma_f32_16x16x32_f16(af[1][kk], bf, acc1, 0, 0, 0);
            }
            const float bv = bfu[cc];
            __half* dstA = (ct < 4) ? xlh : xrh;
            const int ch = (ct & 3) * 16 + m;
#pragma unroll
            for (int r = 0; r < 4; ++r) {
                dstA[(size_t)(i0 + q * 4 + r) * HC + ch]      = __float2half(acc0[r] + bv);
                dstA[(size_t)(i0 + 16 + q * 4 + r) * HC + ch] = __float2half(acc1[r] + bv);
            }
        }
        __syncthreads();
    }
}

// ------------- fused sort + aggregation + epilogue (R20 + f16 xr) -----------
// At its random-gather MLP bound: 105.8MB HBM / 64.3us = 1.69 TB/s. Only
// change: xr read as f16 uint4 (bit-identical; -12.8MB, -8 cvt/node).
__device__ __forceinline__ float redpair(float v) {
    int a = __builtin_amdgcn_update_dpp(0, __float_as_int(v), 0xB1, 0xF, 0xF, true);
    return v + __int_as_float(a);   // quad_perm [1,0,3,2] = xor1
}
__device__ __forceinline__ float red8(float v) {
    int a = __builtin_amdgcn_update_dpp(0, __float_as_int(v), 0x128, 0xF, 0xF, true);
    return v + __int_as_float(a);   // row_ror:8 = lane^8 within 16-lane row
}

__global__ __launch_bounds__(256) void k_aggs(
    const __half* __restrict__ xlh, const __half* __restrict__ xrh,
    const float* __restrict__ att, const float* __restrict__ bias,
    const float* __restrict__ Wh, const float* __restrict__ bh,
    const int* __restrict__ bfill, const unsigned* __restrict__ coarse,
    float* __restrict__ out, int N) {
    __shared__ int s_src[BCAP2];          // 6 KB (worst-case skew safe)
    __shared__ int s_cnt[BKQ], s_off[BKQ], s_cur[BKQ], s_scan[BKQ];
    const int t = threadIdx.x;
    const int bkt  = blockIdx.x >> 2;
    const int quad = blockIdx.x & 3;
    const int eb = bkt * BCAP2;
    const int ee = bfill[bkt];            // eb + bucket edge count
    if (t < BKQ) { s_cnt[t] = 0; s_cur[t] = 0; }
    __syncthreads();
    // stage this quarter's entries in registers (<=6 per thread)
    unsigned er[6]; int nr = 0;
#pragma unroll
    for (int r = 0; r < 6; ++r) {
        const int idx = eb + t + r * 256;
        if (idx < ee) {
            const unsigned e = coarse[idx];
            if (((e >> 4) & 3u) == (unsigned)quad) er[nr++] = e;
        }
    }
    for (int k = 0; k < nr; ++k) atomicAdd(&s_cnt[er[k] & 15], 1);
    __syncthreads();
    if (t < BKQ) s_scan[t] = s_cnt[t];
    __syncthreads();
    for (int o = 1; o < BKQ; o <<= 1) {
        int v = (t < BKQ && t >= o) ? s_scan[t - o] : 0;
        __syncthreads();
        if (t < BKQ) s_scan[t] += v;
        __syncthreads();
    }
    if (t < BKQ) s_off[t] = s_scan[t] - s_cnt[t];
    __syncthreads();
    for (int k = 0; k < nr; ++k) {
        const int bin = er[k] & 15;
        const int pos = atomicAdd(&s_cur[bin], 1);
        s_src[s_off[bin] + pos] = (int)(er[k] >> 6);
    }
    __syncthreads();

    // ---- aggregation phase ----
    const int wave = t >> 6;
    const int lane = t & 63;
    const int sub  = lane & 7;      // channels 8sub..8sub+7
    const int slot = lane >> 3;     // edge slot 0..7
    const _Float16* xlhp = (const _Float16*)xlh;
    const _Float16* xrhp = (const _Float16*)xrh;

    const float4 atA = *(const float4*)(att + 8 * sub);
    const float4 atB = *(const float4*)(att + 8 * sub + 4);
    f16x2 at[4];
    at[0][0] = (_Float16)(atA.x * L2E); at[0][1] = (_Float16)(atA.y * L2E);
    at[1][0] = (_Float16)(atA.z * L2E); at[1][1] = (_Float16)(atA.w * L2E);
    at[2][0] = (_Float16)(atB.x * L2E); at[2][1] = (_Float16)(atB.y * L2E);
    at[3][0] = (_Float16)(atB.z * L2E); at[3][1] = (_Float16)(atB.w * L2E);
    const f16x2 c02 = {(_Float16)NEG_SLOPE, (_Float16)NEG_SLOPE};
    const _Float16 h0 = (_Float16)0.f;
    const float4 biA = *(const float4*)(bias + 8 * sub);
    const float4 biB = *(const float4*)(bias + 8 * sub + 4);
    const float4 whA = *(const float4*)(Wh + 8 * sub);
    const float4 whB = *(const float4*)(Wh + 8 * sub + 4);
    const float bhv = bh[0];

    for (int k4 = 0; k4 < 4; ++k4) {
        const int nl = wave + 4 * k4;             // 0..15, interleaved
        const int i = bkt * 64 + quad * 16 + nl;
        if (i >= N) continue;
        const int beg = s_off[nl];
        const int cnt = s_cnt[nl];

        const uint4 xrraw = *(const uint4*)(xrhp + ((size_t)i << 6) + 8 * sub);
        const uint4 xliraw = *(const uint4*)(xlhp + ((size_t)i << 6) + 8 * sub);
        f16x2 xri[4], xli[4];
        xri[0] = __builtin_bit_cast(f16x2, xrraw.x);
        xri[1] = __builtin_bit_cast(f16x2, xrraw.y);
        xri[2] = __builtin_bit_cast(f16x2, xrraw.z);
        xri[3] = __builtin_bit_cast(f16x2, xrraw.w);
        xli[0] = __builtin_bit_cast(f16x2, xliraw.x);
        xli[1] = __builtin_bit_cast(f16x2, xliraw.y);
        xli[2] = __builtin_bit_cast(f16x2, xliraw.z);
        xli[3] = __builtin_bit_cast(f16x2, xliraw.w);

        float t0 = 0.f;
#pragma unroll
        for (int c = 0; c < 4; ++c) {
            f16x2 w = xli[c] + xri[c];
            w = __builtin_elementwise_max(w, w * c02);
            t0 = __builtin_amdgcn_fdot2(at[c], w, t0, false);
        }
        t0 = redpair(t0);
        const _Float16 pe0h = (slot == 0) ? (_Float16)exp2f(t0) : h0;
        const f16x2 p0A = {pe0h, h0};
        const f16x2 p0B = {h0, pe0h};
        float s = (float)pe0h;
        float a[8];
#pragma unroll
        for (int c = 0; c < 4; ++c) {
            a[2 * c]     = __builtin_amdgcn_fdot2(xli[c], p0A, 0.f, false);
            a[2 * c + 1] = __builtin_amdgcn_fdot2(xli[c], p0B, 0.f, false);
        }

        int p = 0;
#define EDGE_GROUP(JEXPR, PRED)                                              \
    {                                                                        \
        const int jj = (JEXPR);                                              \
        const uint4 raw = *(const uint4*)(xlhp + ((size_t)jj << 6) + 8 * sub);\
        f16x2 xv[4];                                                         \
        xv[0] = __builtin_bit_cast(f16x2, raw.x);                            \
        xv[1] = __builtin_bit_cast(f16x2, raw.y);                            \
        xv[2] = __builtin_bit_cast(f16x2, raw.z);                            \
        xv[3] = __builtin_bit_cast(f16x2, raw.w);                            \
        float tt = 0.f;                                                      \
        _Pragma("unroll")                                                    \
        for (int c = 0; c < 4; ++c) {                                        \
            f16x2 w = xv[c] + xri[c];                                        \
            w = __builtin_elementwise_max(w, w * c02);                       \
            tt = __builtin_amdgcn_fdot2(at[c], w, tt, false);                \
        }                                                                    \
        tt = redpair(tt);                                                    \
        const _Float16 peh = (PRED) ? (_Float16)exp2f(tt) : h0;              \
        const f16x2 pA = {peh, h0};                                          \
        const f16x2 pB = {h0, peh};                                          \
        s += (float)peh;                                                     \
        _Pragma("unroll")                                                    \
        for (int c = 0; c < 4; ++c) {                                        \
            a[2 * c]     = __builtin_amdgcn_fdot2(xv[c], pA, a[2 * c], false);\
            a[2 * c + 1] = __builtin_amdgcn_fdot2(xv[c], pB, a[2 * c + 1], false);\
        }                                                                    \
    }
        for (; p + 16 <= cnt; p += 16) {
            const int j0 = s_src[beg + p + slot];
            const int j1 = s_src[beg + p + 8 + slot];
            EDGE_GROUP(j0, true)
            EDGE_GROUP(j1, true)
        }
        if (p + 8 <= cnt) {
            const int j0 = s_src[beg + p + slot];
            EDGE_GROUP(j0, true)
            p += 8;
        }
        const int rem = cnt - p;
        if (rem > 0) {
            const int idx = p + slot;
            const int j0 = s_src[beg + ((idx < cnt) ? idx : (cnt - 1))];
            EDGE_GROUP(j0, slot < rem)
        }
#undef EDGE_GROUP

        s = red8(s);  s += __shfl_xor(s, 16);  s += __shfl_xor(s, 32);
#pragma unroll
        for (int c = 0; c < 8; ++c) {
            a[c] = red8(a[c]);
            a[c] += __shfl_xor(a[c], 16);
            a[c] += __shfl_xor(a[c], 32);
        }
        const float inv = 1.f / s;
        float y = fmaxf(a[0] * inv + biA.x, 0.f) * whA.x
                + fmaxf(a[1] * inv + biA.y, 0.f) * whA.y
                + fmaxf(a[2] * inv + biA.z, 0.f) * whA.z
                + fmaxf(a[3] * inv + biA.w, 0.f) * whA.w
                + fmaxf(a[4] * inv + biB.x, 0.f) * whB.x
                + fmaxf(a[5] * inv + biB.y, 0.f) * whB.y
                + fmaxf(a[6] * inv + biB.z, 0.f) * whB.z
                + fmaxf(a[7] * inv + biB.w, 0.f) * whB.w;
        y += __shfl_xor(y, 1);
        y += __shfl_xor(y, 2);
        y += __shfl_xor(y, 4);
        if (lane == 0) out[i] = y + bhv;
    }
}

// ---------------- launch ----------------
extern "C" void kernel_launch(void* const* d_in, const int* in_sizes, int n_in,
                              void* d_out, int out_size, void* d_ws, size_t ws_size,
                              hipStream_t stream) {
    const float* x   = (const float*)d_in[0];
    const int*   ei  = (const int*)d_in[1];
    const float* Wl  = (const float*)d_in[2];
    const float* bl  = (const float*)d_in[3];
    const float* Wr  = (const float*)d_in[4];
    const float* br  = (const float*)d_in[5];
    const float* att = (const float*)d_in[6];
    const float* bias= (const float*)d_in[7];
    const float* Wh  = (const float*)d_in[8];
    const float* bh  = (const float*)d_in[9];
    float* out = (float*)d_out;

    const int N = in_sizes[0] / D_IN;      // 100000
    const int E = in_sizes[1] / 2;         // 1600000
    const int* src = ei;
    const int* dst = ei + E;
    const int nbkt = (N + BK - 1) / BK;    // 1563
    const int nscat = (E + 4095) / 4096;   // 391

    // workspace layout (256B aligned)
    auto align = [](size_t v) { return (v + 255) & ~(size_t)255; };
    char* ws = (char*)d_ws;
    size_t off = 0;
    __half* xlh     = (__half*)(ws + off);   off = align(off + (size_t)N * HC * 2);
    __half* xrh     = (__half*)(ws + off);   off = align(off + (size_t)N * HC * 2);
    int*   bfill    = (int*)(ws + off);      off = align(off + NBIN * 4);
    unsigned* coarse= (unsigned*)(ws + off); off = align(off + (size_t)NBIN * BCAP2 * 4);
    (void)ws_size;

    k_iota<<<8, 256, 0, stream>>>(bfill, NBIN);

    k_projscat<<<nscat + 1024, 256, 0, stream>>>(x, Wl, bl, Wr, br, xlh, xrh,
                                                 src, dst, E, bfill, coarse, N);

    k_aggs<<<nbkt * 4, 256, 0, stream>>>(xlh, xrh, att, bias, Wh, bh,
                                         bfill, coarse, out, N);
}